// Round 7
// baseline (90.932 us; speedup 1.0000x reference)
//
#include <hip/hip_runtime.h>
#include <hip/hip_bf16.h>
#include <stdint.h>

#define LL 2048
#define DD 64

typedef __attribute__((ext_vector_type(4))) float    f32x4;
typedef __attribute__((ext_vector_type(16))) float   f32x16;
typedef __attribute__((ext_vector_type(8))) short    short8;
typedef __attribute__((ext_vector_type(4))) int      int4v;
typedef __attribute__((ext_vector_type(4))) unsigned uint4v;

// fp32 -> bf16 round-to-nearest-even
__device__ __forceinline__ short f2bf(float f) {
  unsigned u = __builtin_bit_cast(unsigned, f);
  return (short)((u + 0x7fffu + ((u >> 16) & 1u)) >> 16);
}

// packed fp32x2 -> bf16x2 (RNE), one instruction
__device__ __forceinline__ unsigned cvtpk(float lo, float hi) {
  unsigned r;
  asm("v_cvt_pk_bf16_f32 %0, %1, %2" : "=v"(r) : "v"(lo), "v"(hi));
  return r;
}
// swap: a.hi32lanes <-> b.lo32lanes  => a=[a_lo,b_lo], b=[a_hi,b_hi]
__device__ __forceinline__ void plswap(unsigned &a, unsigned &b) {
  asm volatile("v_permlane32_swap_b32 %0, %1" : "+v"(a), "+v"(b));
}

// ---------------- prepass: K transpose, V transpose, mask bit-pack ----------
__global__ __launch_bounds__(256, 4)
void prep_kernel(const float* __restrict__ k, const float* __restrict__ v,
                 const int* __restrict__ mask, short* __restrict__ ktg,
                 short* __restrict__ vtg, unsigned* __restrict__ mp) {
  __shared__ short Ts[64 * 64];
  const int bid = blockIdx.x;
  const int t = threadIdx.x;

  if (bid < 2048) {
    const bool isK = (bid < 1024);
    const int id   = isK ? bid : bid - 1024;
    const int hd   = id >> 5;
    const int tile = id & 31;
    const size_t base = (size_t)hd * LL * DD;

    const int r  = t >> 2;
    const int c0 = (t & 3) << 4;
    const float* src = isK ? (k + base + (size_t)r * LL + tile * 64 + c0)
                           : (v + base + (size_t)(tile * 64 + r) * DD + c0);
#pragma unroll
    for (int j = 0; j < 16; j += 4) {
      f32x4 f = *(const f32x4*)(src + j);
#pragma unroll
      for (int i2 = 0; i2 < 4; ++i2)
        Ts[(c0 + j + i2) * 64 + r] = f2bf(f[i2]);
    }
    __syncthreads();
    const int ro = t >> 2, co = (t & 3) << 4;
    short* dst = isK ? (ktg + base + (size_t)(tile * 64 + ro) * 64 + co)
                     : (vtg + base + (size_t)ro * LL + tile * 64 + co);
    *(short8*)(dst)     = *(const short8*)&Ts[ro * 64 + co];
    *(short8*)(dst + 8) = *(const short8*)&Ts[ro * 64 + co + 8];
  } else {
    const int w   = (bid - 2048) * 256 + t;
    const int b   = w >> 17;
    const int rem = w & 131071;            // row*64 + wordcol
    const int* src = mask + ((size_t)b << 22) + ((size_t)rem << 5);
    unsigned word = 0;
#pragma unroll
    for (int j = 0; j < 8; ++j) {
      int4v mi = *(const int4v*)(src + j * 4);
      word |= (mi.x != 0 ? 1u : 0u) << (j * 4);
      word |= (mi.y != 0 ? 1u : 0u) << (j * 4 + 1);
      word |= (mi.z != 0 ? 1u : 0u) << (j * 4 + 2);
      word |= (mi.w != 0 ? 1u : 0u) << (j * 4 + 3);
    }
    const int row = rem >> 6, wc = rem & 63;
    // tile-major layout: [b][kt=wc>>1][row][half=wc&1]
    mp[((size_t)b << 17) + (size_t)(wc >> 1) * 4096 + row * 2 + (wc & 1)] = word;
  }
}

// ---- attention: LDS-free, barrier-free; 64 q/wave; in-block split-K --------
// block = 4 waves: (qt2 = wq>>1) selects 64-q tile, (sk = wq&1) selects key half.
// K/V fragments load straight from L2 (16B contiguous in prep layouts).
__global__ __launch_bounds__(256, 2)
void attn_kernel(const float* __restrict__ q, const short* __restrict__ ktg,
                 const short* __restrict__ vtg, const unsigned* __restrict__ mp,
                 float* __restrict__ out) {
  __shared__ float Ox[2][64 * 64];   // raw O partials from sk=1 waves
  __shared__ float Ls[2][64];        // lsum partials from sk=1 waves

  const int t = threadIdx.x, lane = t & 63, wq = t >> 6;
  const int l31 = lane & 31, g = lane >> 5;
  const int qt2 = wq >> 1, sk = wq & 1;

  // XCD swizzle: 64 consecutive logical blocks per XCD
  const int lg = ((blockIdx.x & 7) << 6) + (blockIdx.x >> 3);
  const int qp = lg & 15, hd = lg >> 4, b = hd >> 4;
  const size_t base = (size_t)hd * LL * DD;
  const int q0 = qp * 128 + qt2 * 64;

  // ---- Q B-fragments, 2 sets of 32 q-rows (pre-scaled by 0.125*log2e) ----
  short8 bq[2][4];
  {
    const float qsc = 0.125f * 1.44269504f;
#pragma unroll
    for (int qs = 0; qs < 2; ++qs) {
      const float* qrow = q + base + (size_t)(q0 + qs * 32 + l31) * DD + g * 8;
#pragma unroll
      for (int st = 0; st < 4; ++st) {
        f32x4 f0 = *(const f32x4*)(qrow + st * 16);
        f32x4 f1 = *(const f32x4*)(qrow + st * 16 + 4);
        uint4v u;
        u.x = cvtpk(f0.x * qsc, f0.y * qsc);
        u.y = cvtpk(f0.z * qsc, f0.w * qsc);
        u.z = cvtpk(f1.x * qsc, f1.y * qsc);
        u.w = cvtpk(f1.z * qsc, f1.w * qsc);
        bq[qs][st] = __builtin_bit_cast(short8, u);
      }
    }
  }

  const short* kb_ = ktg + base;                     // [key][d]
  const short* vb_ = vtg + base + (size_t)l31 * LL;  // row dv=l31 of [d][key]

  f32x16 o00 = {}, o01 = {}, o10 = {}, o11 = {};     // [qs][dv-half]
  float ls0 = 0.f, ls1 = 0.f;

  const unsigned long long* mp64 = (const unsigned long long*)mp;
  const unsigned long long* mr0 = mp64 + (size_t)b * 65536 + (q0 + l31);
  const unsigned long long* mr1 = mr0 + 32;

  const int kt0 = sk * 16;
  for (int kt = kt0; kt < kt0 + 16; ++kt) {
    // mask words early (latency hides under QK)
    const unsigned long long mw0 = mr0[(size_t)kt * 2048];
    const unsigned long long mw1 = mr1[(size_t)kt * 2048];

    // ---- QK^T (swapped): S^T[key][q]; A = K frags direct from L2 ----
    f32x16 s00 = {}, s01 = {}, s10 = {}, s11 = {};   // [qs][kh]
    const short* ktp = kb_ + (size_t)kt * 4096 + (size_t)l31 * 64 + g * 8;
    __builtin_amdgcn_s_setprio(1);
#pragma unroll
    for (int st = 0; st < 4; ++st) {
      short8 kf0 = *(const short8*)(ktp + st * 16);             // keys kh=0
      short8 kf1 = *(const short8*)(ktp + 32 * 64 + st * 16);   // keys kh=1
      s00 = __builtin_amdgcn_mfma_f32_32x32x16_bf16(kf0, bq[0][st], s00, 0, 0, 0);
      s10 = __builtin_amdgcn_mfma_f32_32x32x16_bf16(kf0, bq[1][st], s10, 0, 0, 0);
      s01 = __builtin_amdgcn_mfma_f32_32x32x16_bf16(kf1, bq[0][st], s01, 0, 0, 0);
      s11 = __builtin_amdgcn_mfma_f32_32x32x16_bf16(kf1, bq[1][st], s11, 0, 0, 0);
    }
    __builtin_amdgcn_s_setprio(0);

#pragma unroll
    for (int kh = 0; kh < 2; ++kh) {
      // ---- P = exp2(S) or 0, pack to bf16 A-frags for both q-sets ----
      short8 pa[2][2];
#pragma unroll
      for (int qs = 0; qs < 2; ++qs) {
        const unsigned long long mw = qs ? mw1 : mw0;
        const unsigned th = (unsigned)(mw >> (kh * 32)) >> (g * 4);
        f32x16 sv = qs ? (kh ? s11 : s10) : (kh ? s01 : s00);
        float pv_[16];
#pragma unroll
        for (int r = 0; r < 16; ++r) {
          const unsigned bit = 1u << ((r & 3) + 8 * (r >> 2));
          float e = __builtin_amdgcn_exp2f(sv[r]);
          pv_[r] = (th & bit) ? e : 0.f;
        }
        float t0 = (pv_[0] + pv_[1]) + (pv_[2] + pv_[3]);
        float t1 = (pv_[4] + pv_[5]) + (pv_[6] + pv_[7]);
        float t2 = (pv_[8] + pv_[9]) + (pv_[10] + pv_[11]);
        float t3 = (pv_[12] + pv_[13]) + (pv_[14] + pv_[15]);
        if (qs == 0) ls0 += (t0 + t1) + (t2 + t3);
        else         ls1 += (t0 + t1) + (t2 + t3);
        unsigned cc0 = cvtpk(pv_[0],  pv_[1]),  cc1 = cvtpk(pv_[2],  pv_[3]);
        unsigned cc2 = cvtpk(pv_[4],  pv_[5]),  cc3 = cvtpk(pv_[6],  pv_[7]);
        unsigned cc4 = cvtpk(pv_[8],  pv_[9]),  cc5 = cvtpk(pv_[10], pv_[11]);
        unsigned cc6 = cvtpk(pv_[12], pv_[13]), cc7 = cvtpk(pv_[14], pv_[15]);
        plswap(cc0, cc2); plswap(cc1, cc3);
        plswap(cc4, cc6); plswap(cc5, cc7);
        pa[qs][0] = __builtin_bit_cast(short8, (uint4v){cc0, cc1, cc2, cc3});
        pa[qs][1] = __builtin_bit_cast(short8, (uint4v){cc4, cc5, cc6, cc7});
      }
      // ---- PV: B = V frags direct from L2; each frag feeds both q-sets ----
      __builtin_amdgcn_s_setprio(1);
#pragma unroll
      for (int s2 = 0; s2 < 2; ++s2) {
        const int stg = kh * 2 + s2;
        const short* vtp = vb_ + (size_t)kt * 64 + stg * 16 + g * 8;
        short8 v0 = *(const short8*)(vtp);             // dv 0..31 (row l31)
        short8 v1 = *(const short8*)(vtp + 32 * LL);   // dv 32..63
        o00 = __builtin_amdgcn_mfma_f32_32x32x16_bf16(pa[0][s2], v0, o00, 0, 0, 0);
        o01 = __builtin_amdgcn_mfma_f32_32x32x16_bf16(pa[0][s2], v1, o01, 0, 0, 0);
        o10 = __builtin_amdgcn_mfma_f32_32x32x16_bf16(pa[1][s2], v0, o10, 0, 0, 0);
        o11 = __builtin_amdgcn_mfma_f32_32x32x16_bf16(pa[1][s2], v1, o11, 0, 0, 0);
      }
      __builtin_amdgcn_s_setprio(0);
    }
  }

  // ---- combine the two key-split waves through LDS (single barrier) ----
  ls0 += __shfl_xor(ls0, 32);
  ls1 += __shfl_xor(ls1, 32);

  if (sk == 1) {
    float* oxp = &Ox[qt2][0];
#pragma unroll
    for (int r = 0; r < 16; ++r) {
      int crow = (r & 3) + 8 * (r >> 2) + 4 * g;
      oxp[crow * 64 + l31]             = o00[r];
      oxp[crow * 64 + 32 + l31]        = o01[r];
      oxp[(32 + crow) * 64 + l31]      = o10[r];
      oxp[(32 + crow) * 64 + 32 + l31] = o11[r];
    }
    if (g == 0) { Ls[qt2][l31] = ls0; Ls[qt2][32 + l31] = ls1; }
  }
  __syncthreads();
  if (sk == 0) {
    const float linv0 = 1.f / (ls0 + Ls[qt2][l31]);
    const float linv1 = 1.f / (ls1 + Ls[qt2][32 + l31]);
    const float* oxp = &Ox[qt2][0];
    float* ob = out + base + (size_t)q0 * DD;
#pragma unroll
    for (int r = 0; r < 16; ++r) {
      int crow = (r & 3) + 8 * (r >> 2) + 4 * g;
      float li0 = __shfl(linv0, crow);
      float li1 = __shfl(linv1, crow);
      ob[(size_t)crow * DD + l31] =
          (o00[r] + oxp[crow * 64 + l31]) * li0;
      ob[(size_t)crow * DD + 32 + l31] =
          (o01[r] + oxp[crow * 64 + 32 + l31]) * li0;
      ob[(size_t)(32 + crow) * DD + l31] =
          (o10[r] + oxp[(32 + crow) * 64 + l31]) * li1;
      ob[(size_t)(32 + crow) * DD + 32 + l31] =
          (o11[r] + oxp[(32 + crow) * 64 + 32 + l31]) * li1;
    }
  }
}

extern "C" void kernel_launch(void* const* d_in, const int* in_sizes, int n_in,
                              void* d_out, int out_size, void* d_ws, size_t ws_size,
                              hipStream_t stream) {
  const float* q    = (const float*)d_in[0];
  const float* k    = (const float*)d_in[1];
  const float* v    = (const float*)d_in[2];
  const int*   mask = (const int*)d_in[3];
  float* out = (float*)d_out;

  // ws carve: ktg 8.4MB | vtg 8.4MB | mp 1MB
  short*    ktg = (short*)d_ws;
  short*    vtg = ktg + (size_t)32 * LL * DD;
  unsigned* mp  = (unsigned*)(vtg + (size_t)32 * LL * DD);

  prep_kernel<<<3072, 256, 0, stream>>>(k, v, mask, ktg, vtg, mp);
  attn_kernel<<<512, 256, 0, stream>>>(q, ktg, vtg, mp, out);
}

// Round 8
// 80.635 us; speedup vs baseline: 1.1277x; 1.1277x over previous
//
#include <hip/hip_runtime.h>
#include <hip/hip_bf16.h>
#include <stdint.h>

#define LL 2048
#define DD 64
#define NT 32     // K tiles of 64 keys
#define NBUF 4    // LDS ring buffers, prefetch 3 ahead

typedef __attribute__((ext_vector_type(4))) float    f32x4;
typedef __attribute__((ext_vector_type(16))) float   f32x16;
typedef __attribute__((ext_vector_type(8))) short    short8;
typedef __attribute__((ext_vector_type(4))) int      int4v;
typedef __attribute__((ext_vector_type(4))) unsigned uint4v;

#define AS3 __attribute__((address_space(3)))
#define AS1 __attribute__((address_space(1)))

// fp32 -> bf16 round-to-nearest-even
__device__ __forceinline__ short f2bf(float f) {
  unsigned u = __builtin_bit_cast(unsigned, f);
  return (short)((u + 0x7fffu + ((u >> 16) & 1u)) >> 16);
}

// packed fp32x2 -> bf16x2 (RNE), one instruction
__device__ __forceinline__ unsigned cvtpk(float lo, float hi) {
  unsigned r;
  asm("v_cvt_pk_bf16_f32 %0, %1, %2" : "=v"(r) : "v"(lo), "v"(hi));
  return r;
}
// swap: a.hi32lanes <-> b.lo32lanes  => a=[a_lo,b_lo], b=[a_hi,b_hi]
__device__ __forceinline__ void plswap(unsigned &a, unsigned &b) {
  asm volatile("v_permlane32_swap_b32 %0, %1" : "+v"(a), "+v"(b));
}

// ---------------- prepass: K transpose, V transpose, mask bit-pack ----------
__global__ __launch_bounds__(256, 4)
void prep_kernel(const float* __restrict__ k, const float* __restrict__ v,
                 const int* __restrict__ mask, short* __restrict__ ktg,
                 short* __restrict__ vtg, unsigned* __restrict__ mp) {
  __shared__ short Ts[64 * 64];
  const int bid = blockIdx.x;
  const int t = threadIdx.x;

  if (bid < 2048) {
    const bool isK = (bid < 1024);
    const int id   = isK ? bid : bid - 1024;
    const int hd   = id >> 5;
    const int tile = id & 31;
    const size_t base = (size_t)hd * LL * DD;

    const int r  = t >> 2;
    const int c0 = (t & 3) << 4;
    const float* src = isK ? (k + base + (size_t)r * LL + tile * 64 + c0)
                           : (v + base + (size_t)(tile * 64 + r) * DD + c0);
#pragma unroll
    for (int j = 0; j < 16; j += 4) {
      f32x4 f = *(const f32x4*)(src + j);
#pragma unroll
      for (int i2 = 0; i2 < 4; ++i2)
        Ts[(c0 + j + i2) * 64 + r] = f2bf(f[i2]);
    }
    __syncthreads();
    const int ro = t >> 2, co = (t & 3) << 4;
    short* dst = isK ? (ktg + base + (size_t)(tile * 64 + ro) * 64 + co)
                     : (vtg + base + (size_t)ro * LL + tile * 64 + co);
    *(short8*)(dst)     = *(const short8*)&Ts[ro * 64 + co];
    *(short8*)(dst + 8) = *(const short8*)&Ts[ro * 64 + co + 8];
  } else {
    const int w   = (bid - 2048) * 256 + t;
    const int b   = w >> 17;
    const int rem = w & 131071;            // row*64 + wordcol
    const int* src = mask + ((size_t)b << 22) + ((size_t)rem << 5);
    unsigned word = 0;
#pragma unroll
    for (int j = 0; j < 8; ++j) {
      int4v mi = *(const int4v*)(src + j * 4);
      word |= (mi.x != 0 ? 1u : 0u) << (j * 4);
      word |= (mi.y != 0 ? 1u : 0u) << (j * 4 + 1);
      word |= (mi.z != 0 ? 1u : 0u) << (j * 4 + 2);
      word |= (mi.w != 0 ? 1u : 0u) << (j * 4 + 3);
    }
    const int row = rem >> 6, wc = rem & 63;
    // tile-major layout: [b][kt=wc>>1][row][half=wc&1]
    mp[((size_t)b << 17) + (size_t)(wc >> 1) * 4096 + row * 2 + (wc & 1)] = word;
  }
}

// ---- attention: 4-buffer LDS ring, counted vmcnt (T3/T4), lsum via MFMA ----
__global__ __launch_bounds__(256, 2)
void attn_kernel(const float* __restrict__ q, const short* __restrict__ ktg,
                 const short* __restrict__ vtg, const unsigned* __restrict__ mp,
                 float* __restrict__ out) {
  // fragment-major LDS: chunk = fragid*64 + lane, 16B each
  __shared__ short KtF[NBUF][4096];   // frag (kh*4+st): K[key=kh*32+l31][d=st*16+g*8+j]
  __shared__ short VtF[NBUF][4096];   // frag (stg*2+dh): V[key=stg*16+g*8+j][dv=dh*32+l31]

  const int t = threadIdx.x, lane = t & 63, wq = t >> 6;
  const int l31 = lane & 31, g = lane >> 5;

  // XCD swizzle: 64 consecutive logical blocks per XCD (512 % 8 == 0: bijective)
  const int lg = ((blockIdx.x & 7) << 6) + (blockIdx.x >> 3);
  const int qt = lg & 15, hd = lg >> 4, b = hd >> 4;
  const size_t base = (size_t)hd * LL * DD;
  const int q0 = qt * 128 + wq * 32;          // this wave's 32 q rows

  // ---- Q B-fragments (pre-scaled by 0.125*log2e): B[k=d][n=q=l31] ----
  short8 bq[4];
  {
    const float qsc = 0.125f * 1.44269504f;
    const float* qp = q + base + (size_t)(q0 + l31) * DD + g * 8;
#pragma unroll
    for (int st = 0; st < 4; ++st) {
      f32x4 f0 = *(const f32x4*)(qp + st * 16);
      f32x4 f1 = *(const f32x4*)(qp + st * 16 + 4);
      uint4v u;
      u.x = cvtpk(f0.x * qsc, f0.y * qsc);
      u.y = cvtpk(f0.z * qsc, f0.w * qsc);
      u.z = cvtpk(f1.x * qsc, f1.y * qsc);
      u.w = cvtpk(f1.z * qsc, f1.w * qsc);
      bq[st] = __builtin_bit_cast(short8, u);
    }
  }

  // ---- staging source offsets (swizzle decode once; LDS dest stays linear) --
  int kge0, kge1, vge0, vge1;
  {
    int cid0 = wq * 128 + lane, cid1 = cid0 + 64;
    int r0 = cid0 & 31, g0 = (cid0 >> 5) & 1, r1 = cid1 & 31, g1 = (cid1 >> 5) & 1;
    kge0 = ((cid0 >> 8) * 32 + r0) * DD + ((cid0 >> 6) & 3) * 16 + g0 * 8;
    kge1 = ((cid1 >> 8) * 32 + r1) * DD + ((cid1 >> 6) & 3) * 16 + g1 * 8;
    vge0 = (((cid0 >> 6) & 1) * 32 + r0) * LL + (cid0 >> 7) * 16 + g0 * 8;
    vge1 = (((cid1 >> 6) & 1) * 32 + r1) * LL + (cid1 >> 7) * 16 + g1 * 8;
  }
  const short* kthead = ktg + base;
  const short* vthead = vtg + base;

#define STAGE(buf, kt) do { \
  __builtin_amdgcn_global_load_lds((const AS1 uint32_t*)(kthead + (kt)*4096 + kge0), \
      (AS3 uint32_t*)&KtF[buf][(wq*128)*8],    16, 0, 0); \
  __builtin_amdgcn_global_load_lds((const AS1 uint32_t*)(kthead + (kt)*4096 + kge1), \
      (AS3 uint32_t*)&KtF[buf][(wq*128+64)*8], 16, 0, 0); \
  __builtin_amdgcn_global_load_lds((const AS1 uint32_t*)(vthead + (kt)*64 + vge0), \
      (AS3 uint32_t*)&VtF[buf][(wq*128)*8],    16, 0, 0); \
  __builtin_amdgcn_global_load_lds((const AS1 uint32_t*)(vthead + (kt)*64 + vge1), \
      (AS3 uint32_t*)&VtF[buf][(wq*128+64)*8], 16, 0, 0); \
} while (0)

  f32x16 o0 = {}, o1 = {}, ols = {};
  short8 ones;
#pragma unroll
  for (int j = 0; j < 8; ++j) ones[j] = (short)0x3F80;  // bf16 1.0

  const unsigned long long* mrow =
      (const unsigned long long*)mp + (size_t)b * 65536 + (q0 + l31);

  // ---- prologue: mask first, then 3 tiles; drain only mask+tile0 ----
  unsigned long long mw_cur = mrow[0];
  unsigned long long mw_nxt = 0;
  STAGE(0, 0); STAGE(1, 1); STAGE(2, 2);
  asm volatile("s_waitcnt vmcnt(8)" ::: "memory");
  __builtin_amdgcn_s_barrier();

  for (int kt = 0; kt < NT; ++kt) {
    const int cur = kt & 3;
    if (kt + 3 < NT) STAGE((kt + 3) & 3, kt + 3);
    if (kt + 1 < NT) mw_nxt = mrow[(size_t)(kt + 1) * 2048];

    // ---- QK^T (swapped): S^T[key][q], col = q = l31 ----
    f32x16 s0 = {}, s1 = {};
    __builtin_amdgcn_s_setprio(1);
#pragma unroll
    for (int st = 0; st < 4; ++st) {
      short8 ka = *(const short8*)&KtF[cur][(st * 64 + lane) * 8];
      short8 kb = *(const short8*)&KtF[cur][((st + 4) * 64 + lane) * 8];
      s0 = __builtin_amdgcn_mfma_f32_32x32x16_bf16(ka, bq[st], s0, 0, 0, 0);
      s1 = __builtin_amdgcn_mfma_f32_32x32x16_bf16(kb, bq[st], s1, 0, 0, 0);
    }
    __builtin_amdgcn_s_setprio(0);

#pragma unroll
    for (int kh = 0; kh < 2; ++kh) {
      const unsigned th = (unsigned)(mw_cur >> (kh * 32)) >> (g * 4);
      const f32x16 sv = kh ? s1 : s0;
      // key of acc reg r: kh*32 + (r&3) + 8*(r>>2) + 4*g
      float pv_[16];
#pragma unroll
      for (int r = 0; r < 16; ++r) {
        const unsigned bit = 1u << ((r & 3) + 8 * (r >> 2));
        float e = __builtin_amdgcn_exp2f(sv[r]);
        pv_[r] = (th & bit) ? e : 0.f;
      }
      unsigned cc0 = cvtpk(pv_[0],  pv_[1]),  cc1 = cvtpk(pv_[2],  pv_[3]);
      unsigned cc2 = cvtpk(pv_[4],  pv_[5]),  cc3 = cvtpk(pv_[6],  pv_[7]);
      unsigned cc4 = cvtpk(pv_[8],  pv_[9]),  cc5 = cvtpk(pv_[10], pv_[11]);
      unsigned cc6 = cvtpk(pv_[12], pv_[13]), cc7 = cvtpk(pv_[14], pv_[15]);
      // assemble PV A-frags: rows q=l31, k-elems = keys g*8+j (+16 per step)
      plswap(cc0, cc2); plswap(cc1, cc3);
      plswap(cc4, cc6); plswap(cc5, cc7);
      short8 pa0 = __builtin_bit_cast(short8, (uint4v){cc0, cc1, cc2, cc3});
      short8 pa1 = __builtin_bit_cast(short8, (uint4v){cc4, cc5, cc6, cc7});

      __builtin_amdgcn_s_setprio(1);
      // row-sums of P via ones-B MFMA (replaces VALU lsum + epilogue shuffles)
      ols = __builtin_amdgcn_mfma_f32_32x32x16_bf16(pa0, ones, ols, 0, 0, 0);
      ols = __builtin_amdgcn_mfma_f32_32x32x16_bf16(pa1, ones, ols, 0, 0, 0);
#pragma unroll
      for (int s2 = 0; s2 < 2; ++s2) {
        short8 pa = s2 ? pa1 : pa0;
        int stg = kh * 2 + s2;
        short8 v0 = *(const short8*)&VtF[cur][((stg * 2 + 0) * 64 + lane) * 8];
        short8 v1 = *(const short8*)&VtF[cur][((stg * 2 + 1) * 64 + lane) * 8];
        o0 = __builtin_amdgcn_mfma_f32_32x32x16_bf16(pa, v0, o0, 0, 0, 0);
        o1 = __builtin_amdgcn_mfma_f32_32x32x16_bf16(pa, v1, o1, 0, 0, 0);
      }
      __builtin_amdgcn_s_setprio(0);
    }

    // counted wait: tile kt+1 guaranteed landed; kt+2/kt+3 stay in flight
    asm volatile("s_waitcnt vmcnt(9)" ::: "memory");
    __builtin_amdgcn_s_barrier();
    mw_cur = mw_nxt;
  }

  // ---- epilogue: per-lane exact row sums in ols; no shuffles needed ----
  float* ob = out + base + (size_t)q0 * DD;
#pragma unroll
  for (int r = 0; r < 16; ++r) {
    int crow = (r & 3) + 8 * (r >> 2) + 4 * g;   // q row of acc reg r
    float inv = 1.f / ols[r];
    ob[(size_t)crow * DD + l31]      = o0[r] * inv;
    ob[(size_t)crow * DD + 32 + l31] = o1[r] * inv;
  }
}

extern "C" void kernel_launch(void* const* d_in, const int* in_sizes, int n_in,
                              void* d_out, int out_size, void* d_ws, size_t ws_size,
                              hipStream_t stream) {
  const float* q    = (const float*)d_in[0];
  const float* k    = (const float*)d_in[1];
  const float* v    = (const float*)d_in[2];
  const int*   mask = (const int*)d_in[3];
  float* out = (float*)d_out;

  // ws carve: ktg 8.4MB | vtg 8.4MB | mp 1MB
  short*    ktg = (short*)d_ws;
  short*    vtg = ktg + (size_t)32 * LL * DD;
  unsigned* mp  = (unsigned*)(vtg + (size_t)32 * LL * DD);

  prep_kernel<<<3072, 256, 0, stream>>>(k, v, mask, ktg, vtg, mp);
  attn_kernel<<<512, 256, 0, stream>>>(q, ktg, vtg, mp, out);
}

// Round 9
// 75.550 us; speedup vs baseline: 1.2036x; 1.0673x over previous
//
#include <hip/hip_runtime.h>
#include <hip/hip_bf16.h>
#include <stdint.h>

#define LL 2048
#define DD 64

typedef __attribute__((ext_vector_type(4))) float    f32x4;
typedef __attribute__((ext_vector_type(16))) float   f32x16;
typedef __attribute__((ext_vector_type(8))) short    short8;
typedef __attribute__((ext_vector_type(4))) int      int4v;
typedef __attribute__((ext_vector_type(4))) unsigned uint4v;

#define AS3 __attribute__((address_space(3)))
#define AS1 __attribute__((address_space(1)))

// fp32 -> bf16 round-to-nearest-even
__device__ __forceinline__ short f2bf(float f) {
  unsigned u = __builtin_bit_cast(unsigned, f);
  return (short)((u + 0x7fffu + ((u >> 16) & 1u)) >> 16);
}

// packed fp32x2 -> bf16x2 (RNE), one instruction
__device__ __forceinline__ unsigned cvtpk(float lo, float hi) {
  unsigned r;
  asm("v_cvt_pk_bf16_f32 %0, %1, %2" : "=v"(r) : "v"(lo), "v"(hi));
  return r;
}
// swap: a.hi32lanes <-> b.lo32lanes  => a=[a_lo,b_lo], b=[a_hi,b_hi]
__device__ __forceinline__ void plswap(unsigned &a, unsigned &b) {
  asm volatile("v_permlane32_swap_b32 %0, %1" : "+v"(a), "+v"(b));
}

// ---------------- prepass: K transpose, V transpose, mask bit-pack ----------
__global__ __launch_bounds__(256, 4)
void prep_kernel(const float* __restrict__ k, const float* __restrict__ v,
                 const int* __restrict__ mask, short* __restrict__ ktg,
                 short* __restrict__ vtg, unsigned* __restrict__ mp) {
  __shared__ short Ts[64 * 64];
  const int bid = blockIdx.x;
  const int t = threadIdx.x;

  if (bid < 2048) {
    const bool isK = (bid < 1024);
    const int id   = isK ? bid : bid - 1024;
    const int hd   = id >> 5;
    const int tile = id & 31;
    const size_t base = (size_t)hd * LL * DD;

    const int r  = t >> 2;
    const int c0 = (t & 3) << 4;
    const float* src = isK ? (k + base + (size_t)r * LL + tile * 64 + c0)
                           : (v + base + (size_t)(tile * 64 + r) * DD + c0);
#pragma unroll
    for (int j = 0; j < 16; j += 4) {
      f32x4 f = *(const f32x4*)(src + j);
#pragma unroll
      for (int i2 = 0; i2 < 4; ++i2)
        Ts[(c0 + j + i2) * 64 + r] = f2bf(f[i2]);
    }
    __syncthreads();
    const int ro = t >> 2, co = (t & 3) << 4;
    short* dst = isK ? (ktg + base + (size_t)(tile * 64 + ro) * 64 + co)
                     : (vtg + base + (size_t)ro * LL + tile * 64 + co);
    *(short8*)(dst)     = *(const short8*)&Ts[ro * 64 + co];
    *(short8*)(dst + 8) = *(const short8*)&Ts[ro * 64 + co + 8];
  } else {
    const int w   = (bid - 2048) * 256 + t;
    const int b   = w >> 17;
    const int rem = w & 131071;            // row*64 + wordcol
    const int* src = mask + ((size_t)b << 22) + ((size_t)rem << 5);
    unsigned word = 0;
#pragma unroll
    for (int j = 0; j < 8; ++j) {
      int4v mi = *(const int4v*)(src + j * 4);
      word |= (mi.x != 0 ? 1u : 0u) << (j * 4);
      word |= (mi.y != 0 ? 1u : 0u) << (j * 4 + 1);
      word |= (mi.z != 0 ? 1u : 0u) << (j * 4 + 2);
      word |= (mi.w != 0 ? 1u : 0u) << (j * 4 + 3);
    }
    const int row = rem >> 6, wc = rem & 63;
    // tile-major layout: [b][kt=wc>>1][row][half=wc&1]
    mp[((size_t)b << 17) + (size_t)(wc >> 1) * 4096 + row * 2 + (wc & 1)] = word;
  }
}

// ---- attention: in-block split-K=2, 8 waves (4 qg x 2 sk), LDS combine -----
__global__ __launch_bounds__(512, 4)
void attn_kernel(const float* __restrict__ q, const short* __restrict__ ktg,
                 const short* __restrict__ vtg, const unsigned* __restrict__ mp,
                 float* __restrict__ out) {
  // 64KB flat LDS: K(sk,buf) at (sk*2+buf)*4096, V(sk,buf) at 16384+(sk*2+buf)*4096
  // (shorts). Repurposed as float scratch for the split-K combine at the end.
  __shared__ short LB[32768];

  const int t = threadIdx.x, lane = t & 63, wq = t >> 6;
  const int l31 = lane & 31, g = lane >> 5;
  const int qg = wq >> 1, sk = wq & 1;

  // XCD swizzle: 64 consecutive logical blocks per XCD (512 % 8 == 0: bijective)
  const int lg = ((blockIdx.x & 7) << 6) + (blockIdx.x >> 3);
  const int qt = lg & 15, hd = lg >> 4, b = hd >> 4;
  const size_t base = (size_t)hd * LL * DD;
  const int q0 = qt * 128 + qg * 32;          // this wave's 32 q rows

  // ---- Q B-fragments (pre-scaled by 0.125*log2e): B[k=d][n=q=l31] ----
  short8 bq[4];
  {
    const float qsc = 0.125f * 1.44269504f;
    const float* qp = q + base + (size_t)(q0 + l31) * DD + g * 8;
#pragma unroll
    for (int st = 0; st < 4; ++st) {
      f32x4 f0 = *(const f32x4*)(qp + st * 16);
      f32x4 f1 = *(const f32x4*)(qp + st * 16 + 4);
      uint4v u;
      u.x = cvtpk(f0.x * qsc, f0.y * qsc);
      u.y = cvtpk(f0.z * qsc, f0.w * qsc);
      u.z = cvtpk(f1.x * qsc, f1.y * qsc);
      u.w = cvtpk(f1.z * qsc, f1.w * qsc);
      bq[st] = __builtin_bit_cast(short8, u);
    }
  }

  // ---- staging source offsets: wave (qg,sk) stages quarter qg of half sk ----
  int kge0, kge1, vge0, vge1;
  {
    int cid0 = qg * 128 + lane, cid1 = cid0 + 64;
    int r0 = cid0 & 31, g0 = (cid0 >> 5) & 1, r1 = cid1 & 31, g1 = (cid1 >> 5) & 1;
    kge0 = ((cid0 >> 8) * 32 + r0) * DD + ((cid0 >> 6) & 3) * 16 + g0 * 8;
    kge1 = ((cid1 >> 8) * 32 + r1) * DD + ((cid1 >> 6) & 3) * 16 + g1 * 8;
    vge0 = (((cid0 >> 6) & 1) * 32 + r0) * LL + (cid0 >> 7) * 16 + g0 * 8;
    vge1 = (((cid1 >> 6) & 1) * 32 + r1) * LL + (cid1 >> 7) * 16 + g1 * 8;
  }
  const short* kthead = ktg + base;
  const short* vthead = vtg + base;
  const int koff = sk * 2 * 4096;             // LDS base for this sk's K bufs
  const int voff = 16384 + sk * 2 * 4096;

#define STAGE(buf, kt) do { \
  __builtin_amdgcn_global_load_lds((const AS1 uint32_t*)(kthead + (kt)*4096 + kge0), \
      (AS3 uint32_t*)&LB[koff + (buf)*4096 + (qg*128)*8],      16, 0, 0); \
  __builtin_amdgcn_global_load_lds((const AS1 uint32_t*)(kthead + (kt)*4096 + kge1), \
      (AS3 uint32_t*)&LB[koff + (buf)*4096 + (qg*128+64)*8],   16, 0, 0); \
  __builtin_amdgcn_global_load_lds((const AS1 uint32_t*)(vthead + (kt)*64 + vge0), \
      (AS3 uint32_t*)&LB[voff + (buf)*4096 + (qg*128)*8],      16, 0, 0); \
  __builtin_amdgcn_global_load_lds((const AS1 uint32_t*)(vthead + (kt)*64 + vge1), \
      (AS3 uint32_t*)&LB[voff + (buf)*4096 + (qg*128+64)*8],   16, 0, 0); \
} while (0)

  f32x16 o0 = {}, o1 = {}, ols = {};
  short8 ones;
#pragma unroll
  for (int j = 0; j < 8; ++j) ones[j] = (short)0x3F80;  // bf16 1.0

  const unsigned long long* mrow =
      (const unsigned long long*)mp + (size_t)b * 65536 + (q0 + l31);
  const int kt0 = sk * 16;

  // ---- prologue ----
  unsigned long long mw_cur = mrow[(size_t)kt0 * 2048];
  unsigned long long mw_nxt = 0;
  STAGE(0, kt0);
  asm volatile("s_waitcnt vmcnt(0)" ::: "memory");
  __builtin_amdgcn_s_barrier();

  for (int i = 0; i < 16; ++i) {
    const int cur = i & 1;
    if (i + 1 < 16) {
      STAGE(cur ^ 1, kt0 + i + 1);
      mw_nxt = mrow[(size_t)(kt0 + i + 1) * 2048];
    }

    // ---- QK^T (swapped): S^T[key][q], col = q = l31 ----
    f32x16 s0 = {}, s1 = {};
    __builtin_amdgcn_s_setprio(1);
#pragma unroll
    for (int st = 0; st < 4; ++st) {
      short8 ka = *(const short8*)&LB[koff + cur * 4096 + (st * 64 + lane) * 8];
      short8 kb = *(const short8*)&LB[koff + cur * 4096 + ((st + 4) * 64 + lane) * 8];
      s0 = __builtin_amdgcn_mfma_f32_32x32x16_bf16(ka, bq[st], s0, 0, 0, 0);
      s1 = __builtin_amdgcn_mfma_f32_32x32x16_bf16(kb, bq[st], s1, 0, 0, 0);
    }
    __builtin_amdgcn_s_setprio(0);

#pragma unroll
    for (int kh = 0; kh < 2; ++kh) {
      const unsigned th = (unsigned)(mw_cur >> (kh * 32)) >> (g * 4);
      const f32x16 sv = kh ? s1 : s0;
      // key of acc reg r: kh*32 + (r&3) + 8*(r>>2) + 4*g
      float pv_[16];
#pragma unroll
      for (int r = 0; r < 16; ++r) {
        const unsigned bit = 1u << ((r & 3) + 8 * (r >> 2));
        float e = __builtin_amdgcn_exp2f(sv[r]);
        pv_[r] = (th & bit) ? e : 0.f;
      }
      unsigned cc0 = cvtpk(pv_[0],  pv_[1]),  cc1 = cvtpk(pv_[2],  pv_[3]);
      unsigned cc2 = cvtpk(pv_[4],  pv_[5]),  cc3 = cvtpk(pv_[6],  pv_[7]);
      unsigned cc4 = cvtpk(pv_[8],  pv_[9]),  cc5 = cvtpk(pv_[10], pv_[11]);
      unsigned cc6 = cvtpk(pv_[12], pv_[13]), cc7 = cvtpk(pv_[14], pv_[15]);
      // assemble PV A-frags: rows q=l31, k-elems = keys g*8+j (+16 per step)
      plswap(cc0, cc2); plswap(cc1, cc3);
      plswap(cc4, cc6); plswap(cc5, cc7);
      short8 pa0 = __builtin_bit_cast(short8, (uint4v){cc0, cc1, cc2, cc3});
      short8 pa1 = __builtin_bit_cast(short8, (uint4v){cc4, cc5, cc6, cc7});

      __builtin_amdgcn_s_setprio(1);
      // row-sums of P via ones-B MFMA (replaces VALU lsum + epilogue shuffles)
      ols = __builtin_amdgcn_mfma_f32_32x32x16_bf16(pa0, ones, ols, 0, 0, 0);
      ols = __builtin_amdgcn_mfma_f32_32x32x16_bf16(pa1, ones, ols, 0, 0, 0);
#pragma unroll
      for (int s2 = 0; s2 < 2; ++s2) {
        short8 pa = s2 ? pa1 : pa0;
        int stg = kh * 2 + s2;
        short8 v0 = *(const short8*)&LB[voff + cur * 4096 + ((stg * 2 + 0) * 64 + lane) * 8];
        short8 v1 = *(const short8*)&LB[voff + cur * 4096 + ((stg * 2 + 1) * 64 + lane) * 8];
        o0 = __builtin_amdgcn_mfma_f32_32x32x16_bf16(pa, v0, o0, 0, 0, 0);
        o1 = __builtin_amdgcn_mfma_f32_32x32x16_bf16(pa, v1, o1, 0, 0, 0);
      }
      __builtin_amdgcn_s_setprio(0);
    }

    // counted wait: own 4 stage loads landed; mask load may stay in flight
    asm volatile("s_waitcnt vmcnt(1)" ::: "memory");
    __builtin_amdgcn_s_barrier();
    mw_cur = mw_nxt;
  }

  // ---- split-K combine through repurposed LDS ----
  // per qg: 2048 floats O + 32 floats lsum (area 2080 floats)
  float* LF = (float*)LB;
  __syncthreads();   // everyone past compute; LDS free for reuse
  if (sk == 1) {
    float* ox = LF + qg * 2080;
#pragma unroll
    for (int r = 0; r < 16; ++r) {
      int crow = (r & 3) + 8 * (r >> 2) + 4 * g;
      ox[crow * 64 + l31]      = o0[r];
      ox[crow * 64 + 32 + l31] = o1[r];
      if (l31 == 0) ox[2048 + crow] = ols[r];
    }
  }
  __syncthreads();
  if (sk == 0) {
    const float* ox = LF + qg * 2080;
    float* ob = out + base + (size_t)q0 * DD;
#pragma unroll
    for (int r = 0; r < 16; ++r) {
      int crow = (r & 3) + 8 * (r >> 2) + 4 * g;
      float inv = 1.f / (ols[r] + ox[2048 + crow]);
      ob[(size_t)crow * DD + l31]      = (o0[r] + ox[crow * 64 + l31]) * inv;
      ob[(size_t)crow * DD + 32 + l31] = (o1[r] + ox[crow * 64 + 32 + l31]) * inv;
    }
  }
}

extern "C" void kernel_launch(void* const* d_in, const int* in_sizes, int n_in,
                              void* d_out, int out_size, void* d_ws, size_t ws_size,
                              hipStream_t stream) {
  const float* q    = (const float*)d_in[0];
  const float* k    = (const float*)d_in[1];
  const float* v    = (const float*)d_in[2];
  const int*   mask = (const int*)d_in[3];
  float* out = (float*)d_out;

  // ws carve: ktg 8.4MB | vtg 8.4MB | mp 1MB
  short*    ktg = (short*)d_ws;
  short*    vtg = ktg + (size_t)32 * LL * DD;
  unsigned* mp  = (unsigned*)(vtg + (size_t)32 * LL * DD);

  prep_kernel<<<3072, 256, 0, stream>>>(k, v, mask, ktg, vtg, mp);
  attn_kernel<<<512, 512, 0, stream>>>(q, ktg, vtg, mp, out);
}